// Round 4
// baseline (168.898 us; speedup 1.0000x reference)
//
#include <hip/hip_runtime.h>

// Problem constants (fixed by setup_inputs: bs=8, N=M=4096, C=128)
#define BS 8
#define NN 4096
#define MM 4096
#define CC 128
#define XT 128            // x rows per block
#define MT 128            // cols per m-tile
#define MH 2048           // cols per block (m-half)
#define NMT (MH / MT)     // 16 m-tiles per block
#define NXT (NN / XT)     // 32 x-tiles

#define FINF_BITS 0x7F800000u

typedef __attribute__((ext_vector_type(8))) short bf16x8;
typedef __attribute__((ext_vector_type(4))) float f32x4;

// RNE fp32 -> bf16 (inputs are finite normals)
__device__ inline ushort f2bf(float f) {
    unsigned u = __float_as_uint(f);
    unsigned r = (u + 0x7FFFu + ((u >> 16) & 1u)) >> 16;
    return (ushort)r;
}

// ---------------------------------------------------------------------------
// prep: fp32->bf16 copies + exact fp32 row norms + out=0.
// One float4 of x and y per thread; 32-lane segmented shuffle row-reduce.
// ---------------------------------------------------------------------------
__global__ void ch_prep(const float* __restrict__ x, const float* __restrict__ y,
                        ushort* __restrict__ x16, ushort* __restrict__ y16,
                        float* __restrict__ xn, float* __restrict__ yn,
                        float* __restrict__ out) {
    int gid = blockIdx.x * blockDim.x + threadIdx.x;
    size_t i = (size_t)gid * 4;

    float4 v = *(const float4*)(x + i);
    ushort4 o;
    o.x = f2bf(v.x); o.y = f2bf(v.y); o.z = f2bf(v.z); o.w = f2bf(v.w);
    *(ushort4*)(x16 + i) = o;
    float sx = v.x * v.x + v.y * v.y + v.z * v.z + v.w * v.w;

    float4 w = *(const float4*)(y + i);
    ushort4 p;
    p.x = f2bf(w.x); p.y = f2bf(w.y); p.z = f2bf(w.z); p.w = f2bf(w.w);
    *(ushort4*)(y16 + i) = p;
    float sy = w.x * w.x + w.y * w.y + w.z * w.z + w.w * w.w;

#pragma unroll
    for (int mask = 1; mask <= 16; mask <<= 1) {
        sx += __shfl_xor(sx, mask, 64);
        sy += __shfl_xor(sy, mask, 64);
    }
    if ((threadIdx.x & 31) == 0) {
        int row = gid >> 5;
        xn[row] = sx;
        yn[row] = sy;
    }
    if (gid == 0) out[0] = 0.0f;
}

// ---------------------------------------------------------------------------
// main kernel: persistent m-loop, register-resident x fragments, y fragments
// direct from global (L2-resident), NO LDS tiles, NO barriers in the loop.
// Block = 256 thr (4 waves: wm x wn quadrants of a 128x128 tile).
// Per m-tile: 64 MFMAs/wave (4i x 4j x 4k of 16x16x32 bf16).
// Row d^2-mins live in registers across the whole m-range, reduced once.
// Col d^2-mins: LDS atomicMin array (2048 entries), plain-stored to a
// partial buffer at block end. Zero global atomics. sqrt deferred.
// ---------------------------------------------------------------------------
__global__ __launch_bounds__(256, 2) void ch_tile(
    const ushort* __restrict__ X, const ushort* __restrict__ Y,
    const float* __restrict__ xn, const float* __restrict__ yn,
    float* __restrict__ rowpart,   // [BS][2][NN]
    float* __restrict__ colpart) { // [BS][NXT][MM]

    __shared__ unsigned coltile[MH];   // 8 KB
    __shared__ unsigned rowtile[XT];

    const int b  = blockIdx.z;
    const int xt = blockIdx.x;         // 0..31
    const int mh = blockIdx.y;         // 0..1
    const int n0 = xt * XT;
    const int m0 = mh * MH;
    const int tid  = threadIdx.x;
    const int wave = tid >> 6;
    const int lane = tid & 63;
    const int lc   = lane & 15;        // A/B row, C col
    const int quad = lane >> 4;        // k-chunk, C row group
    const int wm = wave >> 1;
    const int wn = wave & 1;

    for (int c = tid; c < MH; c += 256) coltile[c] = FINF_BITS;
    if (tid < XT) rowtile[tid] = FINF_BITS;

    // ---- x fragments + norms: registers for the whole block ----
    const ushort* Xb = X + ((size_t)b * NN + n0) * CC;
    bf16x8 xf[4][4];
#pragma unroll
    for (int i = 0; i < 4; ++i)
#pragma unroll
        for (int kt = 0; kt < 4; ++kt)
            xf[i][kt] = *(const bf16x8*)(Xb + (size_t)(wm * 64 + i * 16 + lc) * CC +
                                         kt * 32 + quad * 8);
    float xnr[4][4];
#pragma unroll
    for (int i = 0; i < 4; ++i) {
        float4 t = *(const float4*)(xn + (size_t)b * NN + n0 + wm * 64 + i * 16 + quad * 4);
        xnr[i][0] = t.x; xnr[i][1] = t.y; xnr[i][2] = t.z; xnr[i][3] = t.w;
    }

    float rm[4][4];
#pragma unroll
    for (int i = 0; i < 4; ++i)
#pragma unroll
        for (int r = 0; r < 4; ++r) rm[i][r] = __builtin_inff();

    __syncthreads();   // coltile init visible before LDS atomics

    const ushort* Yb  = Y + ((size_t)b * MM + m0) * CC;
    const float*  ynb = yn + (size_t)b * MM + m0;

#pragma unroll 1
    for (int mt = 0; mt < NMT; ++mt) {
        const ushort* Ymt = Yb + (size_t)(mt * MT + wn * 64 + lc) * CC + quad * 8;

        f32x4 acc[4][4];
        bf16x8 yf[4];
        // kt = 0: zero-C MFMA (no acc init pass)
#pragma unroll
        for (int j = 0; j < 4; ++j)
            yf[j] = *(const bf16x8*)(Ymt + (size_t)j * 16 * CC);
        const f32x4 z = {0.f, 0.f, 0.f, 0.f};
#pragma unroll
        for (int j = 0; j < 4; ++j)
#pragma unroll
            for (int i = 0; i < 4; ++i)
                acc[i][j] = __builtin_amdgcn_mfma_f32_16x16x32_bf16(xf[i][0], yf[j], z, 0, 0, 0);
#pragma unroll
        for (int kt = 1; kt < 4; ++kt) {
#pragma unroll
            for (int j = 0; j < 4; ++j)
                yf[j] = *(const bf16x8*)(Ymt + (size_t)j * 16 * CC + kt * 32);
#pragma unroll
            for (int j = 0; j < 4; ++j)
#pragma unroll
                for (int i = 0; i < 4; ++i)
                    acc[i][j] = __builtin_amdgcn_mfma_f32_16x16x32_bf16(xf[i][kt], yf[j],
                                                                        acc[i][j], 0, 0, 0);
        }

        // ---- epilogue: d^2 mins (sqrt/clamp deferred) ----
        float ynr[4];
#pragma unroll
        for (int j = 0; j < 4; ++j)
            ynr[j] = ynb[mt * MT + wn * 64 + j * 16 + lc];

        float cmv[4];
#pragma unroll
        for (int j = 0; j < 4; ++j) cmv[j] = __builtin_inff();

#pragma unroll
        for (int i = 0; i < 4; ++i)
#pragma unroll
            for (int j = 0; j < 4; ++j) {
                f32x4 a = acc[i][j];
#pragma unroll
                for (int r = 0; r < 4; ++r) {
                    float d2 = xnr[i][r] + fmaf(-2.0f, a[r], ynr[j]);
                    rm[i][r] = fminf(rm[i][r], d2);
                    cmv[j]   = fminf(cmv[j], d2);
                }
            }

        // col reduce across quads (lanes 16 apart), then LDS atomic
#pragma unroll
        for (int mask = 16; mask <= 32; mask <<= 1)
#pragma unroll
            for (int j = 0; j < 4; ++j)
                cmv[j] = fminf(cmv[j], __shfl_xor(cmv[j], mask, 64));
        if (quad == 0) {
#pragma unroll
            for (int j = 0; j < 4; ++j)
                atomicMin(&coltile[mt * MT + wn * 64 + j * 16 + lc],
                          __float_as_uint(fmaxf(cmv[j], 0.0f)));
        }
    }

    // ---- row reduce across the 16 lc lanes, once per block ----
#pragma unroll
    for (int mask = 1; mask <= 8; mask <<= 1)
#pragma unroll
        for (int i = 0; i < 4; ++i)
#pragma unroll
            for (int r = 0; r < 4; ++r)
                rm[i][r] = fminf(rm[i][r], __shfl_xor(rm[i][r], mask, 64));
    if (lc == 0) {
#pragma unroll
        for (int i = 0; i < 4; ++i)
#pragma unroll
            for (int r = 0; r < 4; ++r)
                atomicMin(&rowtile[wm * 64 + i * 16 + quad * 4 + r],
                          __float_as_uint(fmaxf(rm[i][r], 0.0f)));
    }

    __syncthreads();
    // plain partial stores — zero global atomics
    if (tid < XT)
        rowpart[((size_t)b * 2 + mh) * NN + n0 + tid] = __uint_as_float(rowtile[tid]);
    for (int c = tid; c < MH; c += 256)
        colpart[((size_t)b * NXT + xt) * MM + m0 + c] = __uint_as_float(coltile[c]);
}

// ---------------------------------------------------------------------------
// finalize: reduce partials, apply sqrt, weighted sum.
// ---------------------------------------------------------------------------
__global__ void ch_finalize(const float* __restrict__ rowpart,
                            const float* __restrict__ colpart,
                            const float* __restrict__ w1,
                            const float* __restrict__ w2,
                            float* __restrict__ out) {
    int i = blockIdx.x * blockDim.x + threadIdx.x;
    int stride = gridDim.x * blockDim.x;
    float s = 0.f;
    for (int idx = i; idx < BS * NN; idx += stride) {
        int b = idx >> 12, n = idx & 4095;
        float rv = fminf(rowpart[((size_t)b * 2 + 0) * NN + n],
                         rowpart[((size_t)b * 2 + 1) * NN + n]);
        s += w1[idx] * sqrtf(rv);
        float cv = __builtin_inff();
#pragma unroll 4
        for (int xt = 0; xt < NXT; ++xt)
            cv = fminf(cv, colpart[((size_t)b * NXT + xt) * MM + n]);
        s += w2[idx] * sqrtf(cv);
    }
#pragma unroll
    for (int off = 32; off > 0; off >>= 1) s += __shfl_down(s, off, 64);
    __shared__ float ls[4];
    int lane = threadIdx.x & 63, wv = threadIdx.x >> 6;
    if (lane == 0) ls[wv] = s;
    __syncthreads();
    if (threadIdx.x == 0) {
        float t = ls[0] + ls[1] + ls[2] + ls[3];
        atomicAdd(out, 0.5f * t);
    }
}

extern "C" void kernel_launch(void* const* d_in, const int* in_sizes, int n_in,
                              void* d_out, int out_size, void* d_ws, size_t ws_size,
                              hipStream_t stream) {
    const float* set1 = (const float*)d_in[0];
    const float* set2 = (const float*)d_in[1];
    const float* w1   = (const float*)d_in[2];
    const float* w2   = (const float*)d_in[3];
    float* out = (float*)d_out;

    // workspace layout (~20.5 MiB)
    ushort* x16     = (ushort*)d_ws;                         // BS*NN*CC bf16 (8 MB)
    ushort* y16     = x16 + (size_t)BS * NN * CC;            // 8 MB
    float*  xn      = (float*)(y16 + (size_t)BS * MM * CC);  // 128 KB
    float*  yn      = xn + BS * NN;                          // 128 KB
    float*  rowpart = yn + BS * MM;                          // BS*2*NN   (256 KB)
    float*  colpart = rowpart + (size_t)BS * 2 * NN;         // BS*NXT*MM (4 MB)

    ch_prep<<<BS * NN * CC / 4 / 256, 256, 0, stream>>>(
        set1, set2, x16, y16, xn, yn, out);

    dim3 grid(NXT, 2, BS);
    ch_tile<<<grid, 256, 0, stream>>>(x16, y16, xn, yn, rowpart, colpart);

    ch_finalize<<<32, 256, 0, stream>>>(rowpart, colpart, w1, w2, out);
}